// Round 1
// baseline (875.939 us; speedup 1.0000x reference)
//
#include <hip/hip_runtime.h>
#include <hip/hip_bf16.h>

#define NOUT 7
#define NCH 256

__global__ __launch_bounds__(256) void pooler_kernel(
    const float* __restrict__ f0, const float* __restrict__ f1,
    const float* __restrict__ f2, const float* __restrict__ f3,
    const float* __restrict__ boxes, const int* __restrict__ bidx,
    float* __restrict__ out, int nbox)
{
    const int n = blockIdx.x;
    if (n >= nbox) return;
    const int c = threadIdx.x;   // one channel per thread, C == 256 == blockDim.x

    // ---- box params (uniform across the block) ----
    const float bx1 = boxes[4*n+0];
    const float by1 = boxes[4*n+1];
    const float bx2 = boxes[4*n+2];
    const float by2 = boxes[4*n+3];

    const float ww = bx2 - bx1 + 1.0f;
    const float hh = by2 - by1 + 1.0f;
    const float s  = sqrtf(ww * hh);
    int lvl = (int)floorf(4.0f + log2f(1e-6f + s * (1.0f / 224.0f)));
    lvl = min(max(lvl, 2), 5) - 2;

    const float* f;
    int H, W;
    float scale;
    if (lvl == 0)      { f = f0; H = 200; W = 304; scale = 0.25f;    }
    else if (lvl == 1) { f = f1; H = 100; W = 152; scale = 0.125f;   }
    else if (lvl == 2) { f = f2; H = 50;  W = 76;  scale = 0.0625f;  }
    else               { f = f3; H = 25;  W = 38;  scale = 0.03125f; }

    const int b = bidx[n];
    const float* __restrict__ fb = f + ((size_t)b * NCH + c) * (size_t)(H * W);

    const float x1 = bx1 * scale;
    const float y1 = by1 * scale;
    const float x2 = bx2 * scale;
    const float y2 = by2 * scale;
    const float roi_w = fmaxf(x2 - x1, 1.0f);
    const float roi_h = fmaxf(y2 - y1, 1.0f);
    const float bw = roi_w * (1.0f / NOUT);
    const float bh = roi_h * (1.0f / NOUT);

    const float Hf = (float)H, Wf = (float)W;

    float* __restrict__ outc = out + ((size_t)n * NCH + c) * (NOUT * NOUT);

    for (int py = 0; py < NOUT; ++py) {
        for (int px = 0; px < NOUT; ++px) {
            float acc = 0.0f;
            #pragma unroll
            for (int iy = 0; iy < 2; ++iy) {
                #pragma unroll
                for (int ix = 0; ix < 2; ++ix) {
                    float y = y1 + ((float)py + 0.25f + 0.5f * (float)iy) * bh;
                    float x = x1 + ((float)px + 0.25f + 0.5f * (float)ix) * bw;
                    const bool valid = (y >= -1.0f) && (y <= Hf) && (x >= -1.0f) && (x <= Wf);
                    y = fminf(fmaxf(y, 0.0f), Hf - 1.0f);
                    x = fminf(fmaxf(x, 0.0f), Wf - 1.0f);
                    const int y0 = (int)floorf(y);
                    const int x0 = (int)floorf(x);
                    const int y1i = min(y0 + 1, H - 1);
                    const int x1i = min(x0 + 1, W - 1);
                    const float ly = y - (float)y0;
                    const float lx = x - (float)x0;
                    const float hy = 1.0f - ly;
                    const float hx = 1.0f - lx;
                    const float v00 = fb[y0  * W + x0 ];
                    const float v01 = fb[y0  * W + x1i];
                    const float v10 = fb[y1i * W + x0 ];
                    const float v11 = fb[y1i * W + x1i];
                    float v = hy * hx * v00 + hy * lx * v01
                            + ly * hx * v10 + ly * lx * v11;
                    acc += valid ? v : 0.0f;
                }
            }
            outc[py * NOUT + px] = acc * 0.25f;
        }
    }
}

extern "C" void kernel_launch(void* const* d_in, const int* in_sizes, int n_in,
                              void* d_out, int out_size, void* d_ws, size_t ws_size,
                              hipStream_t stream) {
    const float* f0    = (const float*)d_in[0];
    const float* f1    = (const float*)d_in[1];
    const float* f2    = (const float*)d_in[2];
    const float* f3    = (const float*)d_in[3];
    const float* boxes = (const float*)d_in[4];
    const int*   bidx  = (const int*)d_in[5];
    float*       out   = (float*)d_out;

    const int nbox = in_sizes[5];   // batch_ids element count == N boxes

    pooler_kernel<<<nbox, 256, 0, stream>>>(f0, f1, f2, f3, boxes, bidx, out, nbox);
}

// Round 2
// 141.206 us; speedup vs baseline: 6.2033x; 6.2033x over previous
//
#include <hip/hip_runtime.h>
#include <hip/hip_bf16.h>

#define NOUT 7
#define NBIN 49
#define NCH 256

// ---------------- NCHW -> NHWC tiled transpose (one level) ----------------
__global__ __launch_bounds__(256) void transpose_kernel(
    const float* __restrict__ in, float* __restrict__ out, int HW)
{
    __shared__ float tile[64][65];
    const int p0 = blockIdx.x * 64;
    const int c0 = blockIdx.y * 64;
    const int b  = blockIdx.z;
    const int tp = threadIdx.x & 63;   // fast lane index
    const int tq = threadIdx.x >> 6;   // 0..3 (wave id)

    const size_t inb = (size_t)b * NCH * (size_t)HW;
    if (p0 + tp < HW) {
        #pragma unroll
        for (int cc = 0; cc < 64; cc += 4) {
            tile[cc + tq][tp] = in[inb + (size_t)(c0 + cc + tq) * HW + (p0 + tp)];
        }
    }
    __syncthreads();
    const size_t outb = (size_t)b * (size_t)HW * NCH;
    #pragma unroll
    for (int pp = 0; pp < 64; pp += 4) {
        const int p = p0 + pp + tq;
        if (p < HW) out[outb + (size_t)p * NCH + (c0 + tp)] = tile[tp][pp + tq];
    }
}

// ---------------- pooling from NHWC, coalesced reads + LDS-staged writes ----------------
__global__ __launch_bounds__(256) void pool_nhwc_kernel(
    const float* __restrict__ ws, const float* __restrict__ boxes,
    const int* __restrict__ bidx, float* __restrict__ out, int nbox)
{
    __shared__ float so[NBIN * 257];   // [bin][channel], padded stride 257

    const int n = blockIdx.x;
    if (n >= nbox) return;
    const int c = threadIdx.x;

    // ---- box params (uniform across the block) ----
    const float bx1 = boxes[4*n+0];
    const float by1 = boxes[4*n+1];
    const float bx2 = boxes[4*n+2];
    const float by2 = boxes[4*n+3];

    const float ww = bx2 - bx1 + 1.0f;
    const float hh = by2 - by1 + 1.0f;
    const float s  = sqrtf(ww * hh);
    int lvl = (int)floorf(4.0f + log2f(1e-6f + s * (1.0f / 224.0f)));
    lvl = min(max(lvl, 2), 5) - 2;

    int H, W;
    float scale;
    size_t off;
    if (lvl == 0)      { H = 200; W = 304; scale = 0.25f;    off = 0;        }
    else if (lvl == 1) { H = 100; W = 152; scale = 0.125f;   off = 31129600; }
    else if (lvl == 2) { H = 50;  W = 76;  scale = 0.0625f;  off = 38912000; }
    else               { H = 25;  W = 38;  scale = 0.03125f; off = 40857600; }

    const int b = bidx[n];
    const float* __restrict__ fb = ws + off + (size_t)b * (size_t)(H * W) * NCH + c;

    const float x1 = bx1 * scale;
    const float y1 = by1 * scale;
    const float x2 = bx2 * scale;
    const float y2 = by2 * scale;
    const float roi_w = fmaxf(x2 - x1, 1.0f);
    const float roi_h = fmaxf(y2 - y1, 1.0f);
    const float bw = roi_w * (1.0f / NOUT);
    const float bh = roi_h * (1.0f / NOUT);

    const float Hf = (float)H, Wf = (float)W;

    for (int py = 0; py < NOUT; ++py) {
        for (int px = 0; px < NOUT; ++px) {
            float acc = 0.0f;
            #pragma unroll
            for (int iy = 0; iy < 2; ++iy) {
                #pragma unroll
                for (int ix = 0; ix < 2; ++ix) {
                    float y = y1 + ((float)py + 0.25f + 0.5f * (float)iy) * bh;
                    float x = x1 + ((float)px + 0.25f + 0.5f * (float)ix) * bw;
                    const bool valid = (y >= -1.0f) && (y <= Hf) && (x >= -1.0f) && (x <= Wf);
                    y = fminf(fmaxf(y, 0.0f), Hf - 1.0f);
                    x = fminf(fmaxf(x, 0.0f), Wf - 1.0f);
                    const int y0 = (int)floorf(y);
                    const int x0 = (int)floorf(x);
                    const int y1i = min(y0 + 1, H - 1);
                    const int x1i = min(x0 + 1, W - 1);
                    const float ly = y - (float)y0;
                    const float lx = x - (float)x0;
                    const float hy = 1.0f - ly;
                    const float hx = 1.0f - lx;
                    const float v00 = fb[((size_t)(y0  * W + x0 )) * NCH];
                    const float v01 = fb[((size_t)(y0  * W + x1i)) * NCH];
                    const float v10 = fb[((size_t)(y1i * W + x0 )) * NCH];
                    const float v11 = fb[((size_t)(y1i * W + x1i)) * NCH];
                    float v = hy * hx * v00 + hy * lx * v01
                            + ly * hx * v10 + ly * lx * v11;
                    acc += valid ? v : 0.0f;
                }
            }
            so[(py * NOUT + px) * 257 + c] = acc * 0.25f;
        }
    }
    __syncthreads();

    // coalesced linear write of this box's (256,7,7) output block
    float* __restrict__ outn = out + (size_t)n * (NCH * NBIN);
    for (int k = threadIdx.x; k < NCH * NBIN; k += 256) {
        const int cb = k / NBIN;
        const int e  = k - cb * NBIN;
        outn[k] = so[e * 257 + cb];
    }
}

// ---------------- fallback (round-1 kernel) if ws too small ----------------
__global__ __launch_bounds__(256) void pooler_kernel(
    const float* __restrict__ f0, const float* __restrict__ f1,
    const float* __restrict__ f2, const float* __restrict__ f3,
    const float* __restrict__ boxes, const int* __restrict__ bidx,
    float* __restrict__ out, int nbox)
{
    const int n = blockIdx.x;
    if (n >= nbox) return;
    const int c = threadIdx.x;

    const float bx1 = boxes[4*n+0];
    const float by1 = boxes[4*n+1];
    const float bx2 = boxes[4*n+2];
    const float by2 = boxes[4*n+3];

    const float ww = bx2 - bx1 + 1.0f;
    const float hh = by2 - by1 + 1.0f;
    const float s  = sqrtf(ww * hh);
    int lvl = (int)floorf(4.0f + log2f(1e-6f + s * (1.0f / 224.0f)));
    lvl = min(max(lvl, 2), 5) - 2;

    const float* f;
    int H, W;
    float scale;
    if (lvl == 0)      { f = f0; H = 200; W = 304; scale = 0.25f;    }
    else if (lvl == 1) { f = f1; H = 100; W = 152; scale = 0.125f;   }
    else if (lvl == 2) { f = f2; H = 50;  W = 76;  scale = 0.0625f;  }
    else               { f = f3; H = 25;  W = 38;  scale = 0.03125f; }

    const int b = bidx[n];
    const float* __restrict__ fb = f + ((size_t)b * NCH + c) * (size_t)(H * W);

    const float x1 = bx1 * scale;
    const float y1 = by1 * scale;
    const float x2 = bx2 * scale;
    const float y2 = by2 * scale;
    const float roi_w = fmaxf(x2 - x1, 1.0f);
    const float roi_h = fmaxf(y2 - y1, 1.0f);
    const float bw = roi_w * (1.0f / NOUT);
    const float bh = roi_h * (1.0f / NOUT);

    const float Hf = (float)H, Wf = (float)W;
    float* __restrict__ outc = out + ((size_t)n * NCH + c) * NBIN;

    for (int py = 0; py < NOUT; ++py) {
        for (int px = 0; px < NOUT; ++px) {
            float acc = 0.0f;
            #pragma unroll
            for (int iy = 0; iy < 2; ++iy) {
                #pragma unroll
                for (int ix = 0; ix < 2; ++ix) {
                    float y = y1 + ((float)py + 0.25f + 0.5f * (float)iy) * bh;
                    float x = x1 + ((float)px + 0.25f + 0.5f * (float)ix) * bw;
                    const bool valid = (y >= -1.0f) && (y <= Hf) && (x >= -1.0f) && (x <= Wf);
                    y = fminf(fmaxf(y, 0.0f), Hf - 1.0f);
                    x = fminf(fmaxf(x, 0.0f), Wf - 1.0f);
                    const int y0 = (int)floorf(y);
                    const int x0 = (int)floorf(x);
                    const int y1i = min(y0 + 1, H - 1);
                    const int x1i = min(x0 + 1, W - 1);
                    const float ly = y - (float)y0;
                    const float lx = x - (float)x0;
                    const float hy = 1.0f - ly;
                    const float hx = 1.0f - lx;
                    const float v00 = fb[y0  * W + x0 ];
                    const float v01 = fb[y0  * W + x1i];
                    const float v10 = fb[y1i * W + x0 ];
                    const float v11 = fb[y1i * W + x1i];
                    float v = hy * hx * v00 + hy * lx * v01
                            + ly * hx * v10 + ly * lx * v11;
                    acc += valid ? v : 0.0f;
                }
            }
            outc[py * NOUT + px] = acc * 0.25f;
        }
    }
}

extern "C" void kernel_launch(void* const* d_in, const int* in_sizes, int n_in,
                              void* d_out, int out_size, void* d_ws, size_t ws_size,
                              hipStream_t stream) {
    const float* f0    = (const float*)d_in[0];
    const float* f1    = (const float*)d_in[1];
    const float* f2    = (const float*)d_in[2];
    const float* f3    = (const float*)d_in[3];
    const float* boxes = (const float*)d_in[4];
    const int*   bidx  = (const int*)d_in[5];
    float*       out   = (float*)d_out;

    const int nbox = in_sizes[5];

    const size_t NEED = 41344000ull * sizeof(float);  // all 4 levels NHWC
    if (ws_size >= NEED) {
        float* t = (float*)d_ws;
        // level dims: (200,304) (100,152) (50,76) (25,38), B=2, C=256
        transpose_kernel<<<dim3(950, 4, 2), 256, 0, stream>>>(f0, t + 0,        60800);
        transpose_kernel<<<dim3(238, 4, 2), 256, 0, stream>>>(f1, t + 31129600, 15200);
        transpose_kernel<<<dim3( 60, 4, 2), 256, 0, stream>>>(f2, t + 38912000, 3800);
        transpose_kernel<<<dim3( 15, 4, 2), 256, 0, stream>>>(f3, t + 40857600, 950);
        pool_nhwc_kernel<<<nbox, 256, 0, stream>>>(t, boxes, bidx, out, nbox);
    } else {
        pooler_kernel<<<nbox, 256, 0, stream>>>(f0, f1, f2, f3, boxes, bidx, out, nbox);
    }
}

// Round 3
// 106.515 us; speedup vs baseline: 8.2236x; 1.3257x over previous
//
#include <hip/hip_runtime.h>
#include <hip/hip_bf16.h>

#define NOUT 7
#define NBIN 49
#define NCH 256

__device__ inline float bf2f(unsigned short u) {
    return __uint_as_float(((unsigned int)u) << 16);
}

// ---------------- NCHW f32 -> NHWC bf16 tiled transpose (one level) ----------------
__global__ __launch_bounds__(256) void transpose_bf16_kernel(
    const float* __restrict__ in, __hip_bfloat16* __restrict__ out, int HW)
{
    __shared__ float tile[64][65];
    const int p0 = blockIdx.x * 64;
    const int c0 = blockIdx.y * 64;
    const int b  = blockIdx.z;
    const int tp = threadIdx.x & 63;
    const int tq = threadIdx.x >> 6;

    const size_t inb = (size_t)b * NCH * (size_t)HW;
    if (p0 + tp < HW) {
        #pragma unroll
        for (int cc = 0; cc < 64; cc += 4) {
            tile[cc + tq][tp] = in[inb + (size_t)(c0 + cc + tq) * HW + (p0 + tp)];
        }
    }
    __syncthreads();
    const size_t outb = (size_t)b * (size_t)HW * NCH;
    #pragma unroll
    for (int pp = 0; pp < 64; pp += 4) {
        const int p = p0 + pp + tq;
        if (p < HW)
            out[outb + (size_t)p * NCH + (c0 + tp)] = __float2bfloat16(tile[tp][pp + tq]);
    }
}

// ---------------- pooling from NHWC bf16: wave-per-bin, 128 ch per block ----------------
__global__ __launch_bounds__(256) void pool_nhwc_bf16_kernel(
    const unsigned short* __restrict__ ws, const float* __restrict__ boxes,
    const int* __restrict__ bidx, float* __restrict__ out, int nbox)
{
    __shared__ __align__(16) float so[128 * NBIN];   // [c_local][bin], exact layout

    const int n = blockIdx.x;
    if (n >= nbox) return;
    const int chalf = blockIdx.y << 7;        // 0 or 128
    const int lane = threadIdx.x & 63;
    const int wave = threadIdx.x >> 6;

    // ---- box params (uniform) ----
    const float bx1 = boxes[4*n+0];
    const float by1 = boxes[4*n+1];
    const float bx2 = boxes[4*n+2];
    const float by2 = boxes[4*n+3];

    const float ww = bx2 - bx1 + 1.0f;
    const float hh = by2 - by1 + 1.0f;
    const float s  = sqrtf(ww * hh);
    int lvl = (int)floorf(4.0f + log2f(1e-6f + s * (1.0f / 224.0f)));
    lvl = min(max(lvl, 2), 5) - 2;

    int H, W;
    float scale;
    size_t off;
    if (lvl == 0)      { H = 200; W = 304; scale = 0.25f;    off = 0;        }
    else if (lvl == 1) { H = 100; W = 152; scale = 0.125f;   off = 31129600; }
    else if (lvl == 2) { H = 50;  W = 76;  scale = 0.0625f;  off = 38912000; }
    else               { H = 25;  W = 38;  scale = 0.03125f; off = 40857600; }

    const int b = bidx[n];
    const unsigned short* __restrict__ fb =
        ws + off + (size_t)b * (size_t)(H * W) * NCH + chalf + 2 * lane;

    const float x1 = bx1 * scale;
    const float y1 = by1 * scale;
    const float x2 = bx2 * scale;
    const float y2 = by2 * scale;
    const float roi_w = fmaxf(x2 - x1, 1.0f);
    const float roi_h = fmaxf(y2 - y1, 1.0f);
    const float bw = roi_w * (1.0f / NOUT);
    const float bh = roi_h * (1.0f / NOUT);

    const float Hf = (float)H, Wf = (float)W;

    for (int e = wave; e < NBIN; e += 4) {
        const int py = e / NOUT;
        const int px = e - py * NOUT;
        float acc0 = 0.0f, acc1 = 0.0f;
        #pragma unroll
        for (int iy = 0; iy < 2; ++iy) {
            #pragma unroll
            for (int ix = 0; ix < 2; ++ix) {
                float y = y1 + ((float)py + 0.25f + 0.5f * (float)iy) * bh;
                float x = x1 + ((float)px + 0.25f + 0.5f * (float)ix) * bw;
                const bool valid = (y >= -1.0f) && (y <= Hf) && (x >= -1.0f) && (x <= Wf);
                y = fminf(fmaxf(y, 0.0f), Hf - 1.0f);
                x = fminf(fmaxf(x, 0.0f), Wf - 1.0f);
                const int y0 = (int)floorf(y);
                const int x0 = (int)floorf(x);
                const int y1i = min(y0 + 1, H - 1);
                const int x1i = min(x0 + 1, W - 1);
                const float ly = y - (float)y0;
                const float lx = x - (float)x0;
                const float hy = 1.0f - ly;
                const float hx = 1.0f - lx;
                const float w00 = hy * hx, w01 = hy * lx, w10 = ly * hx, w11 = ly * lx;

                const ushort2 u00 = *(const ushort2*)(fb + (size_t)(y0  * W + x0 ) * NCH);
                const ushort2 u01 = *(const ushort2*)(fb + (size_t)(y0  * W + x1i) * NCH);
                const ushort2 u10 = *(const ushort2*)(fb + (size_t)(y1i * W + x0 ) * NCH);
                const ushort2 u11 = *(const ushort2*)(fb + (size_t)(y1i * W + x1i) * NCH);

                const float v0 = w00 * bf2f(u00.x) + w01 * bf2f(u01.x)
                               + w10 * bf2f(u10.x) + w11 * bf2f(u11.x);
                const float v1 = w00 * bf2f(u00.y) + w01 * bf2f(u01.y)
                               + w10 * bf2f(u10.y) + w11 * bf2f(u11.y);
                if (valid) { acc0 += v0; acc1 += v1; }
            }
        }
        so[(2 * lane)     * NBIN + e] = acc0 * 0.25f;
        so[(2 * lane + 1) * NBIN + e] = acc1 * 0.25f;
    }
    __syncthreads();

    // coalesced float4 write of this (box, channel-half): 128*49 f32 contiguous
    float* __restrict__ outn = out + (size_t)n * (NCH * NBIN) + (size_t)chalf * NBIN;
    const float4* __restrict__ sof = (const float4*)so;
    for (int idx = threadIdx.x; idx < (128 * NBIN) / 4; idx += 256) {
        ((float4*)outn)[idx] = sof[idx];
    }
}

// ---------------- fallback (round-1 kernel) if ws too small ----------------
__global__ __launch_bounds__(256) void pooler_kernel(
    const float* __restrict__ f0, const float* __restrict__ f1,
    const float* __restrict__ f2, const float* __restrict__ f3,
    const float* __restrict__ boxes, const int* __restrict__ bidx,
    float* __restrict__ out, int nbox)
{
    const int n = blockIdx.x;
    if (n >= nbox) return;
    const int c = threadIdx.x;

    const float bx1 = boxes[4*n+0];
    const float by1 = boxes[4*n+1];
    const float bx2 = boxes[4*n+2];
    const float by2 = boxes[4*n+3];

    const float ww = bx2 - bx1 + 1.0f;
    const float hh = by2 - by1 + 1.0f;
    const float s  = sqrtf(ww * hh);
    int lvl = (int)floorf(4.0f + log2f(1e-6f + s * (1.0f / 224.0f)));
    lvl = min(max(lvl, 2), 5) - 2;

    const float* f;
    int H, W;
    float scale;
    if (lvl == 0)      { f = f0; H = 200; W = 304; scale = 0.25f;    }
    else if (lvl == 1) { f = f1; H = 100; W = 152; scale = 0.125f;   }
    else if (lvl == 2) { f = f2; H = 50;  W = 76;  scale = 0.0625f;  }
    else               { f = f3; H = 25;  W = 38;  scale = 0.03125f; }

    const int b = bidx[n];
    const float* __restrict__ fb = f + ((size_t)b * NCH + c) * (size_t)(H * W);

    const float x1 = bx1 * scale;
    const float y1 = by1 * scale;
    const float x2 = bx2 * scale;
    const float y2 = by2 * scale;
    const float roi_w = fmaxf(x2 - x1, 1.0f);
    const float roi_h = fmaxf(y2 - y1, 1.0f);
    const float bw = roi_w * (1.0f / NOUT);
    const float bh = roi_h * (1.0f / NOUT);

    const float Hf = (float)H, Wf = (float)W;
    float* __restrict__ outc = out + ((size_t)n * NCH + c) * NBIN;

    for (int py = 0; py < NOUT; ++py) {
        for (int px = 0; px < NOUT; ++px) {
            float acc = 0.0f;
            #pragma unroll
            for (int iy = 0; iy < 2; ++iy) {
                #pragma unroll
                for (int ix = 0; ix < 2; ++ix) {
                    float y = y1 + ((float)py + 0.25f + 0.5f * (float)iy) * bh;
                    float x = x1 + ((float)px + 0.25f + 0.5f * (float)ix) * bw;
                    const bool valid = (y >= -1.0f) && (y <= Hf) && (x >= -1.0f) && (x <= Wf);
                    y = fminf(fmaxf(y, 0.0f), Hf - 1.0f);
                    x = fminf(fmaxf(x, 0.0f), Wf - 1.0f);
                    const int y0 = (int)floorf(y);
                    const int x0 = (int)floorf(x);
                    const int y1i = min(y0 + 1, H - 1);
                    const int x1i = min(x0 + 1, W - 1);
                    const float ly = y - (float)y0;
                    const float lx = x - (float)x0;
                    const float hy = 1.0f - ly;
                    const float hx = 1.0f - lx;
                    const float v00 = fb[y0  * W + x0 ];
                    const float v01 = fb[y0  * W + x1i];
                    const float v10 = fb[y1i * W + x0 ];
                    const float v11 = fb[y1i * W + x1i];
                    float v = hy * hx * v00 + hy * lx * v01
                            + ly * hx * v10 + ly * lx * v11;
                    acc += valid ? v : 0.0f;
                }
            }
            outc[py * NOUT + px] = acc * 0.25f;
        }
    }
}

extern "C" void kernel_launch(void* const* d_in, const int* in_sizes, int n_in,
                              void* d_out, int out_size, void* d_ws, size_t ws_size,
                              hipStream_t stream) {
    const float* f0    = (const float*)d_in[0];
    const float* f1    = (const float*)d_in[1];
    const float* f2    = (const float*)d_in[2];
    const float* f3    = (const float*)d_in[3];
    const float* boxes = (const float*)d_in[4];
    const int*   bidx  = (const int*)d_in[5];
    float*       out   = (float*)d_out;

    const int nbox = in_sizes[5];

    const size_t NEED = 41344000ull * sizeof(__hip_bfloat16);  // 82.7 MB
    if (ws_size >= NEED) {
        __hip_bfloat16* t = (__hip_bfloat16*)d_ws;
        // level dims: (200,304) (100,152) (50,76) (25,38), B=2, C=256
        transpose_bf16_kernel<<<dim3(950, 4, 2), 256, 0, stream>>>(f0, t + 0,        60800);
        transpose_bf16_kernel<<<dim3(238, 4, 2), 256, 0, stream>>>(f1, t + 31129600, 15200);
        transpose_bf16_kernel<<<dim3( 60, 4, 2), 256, 0, stream>>>(f2, t + 38912000, 3800);
        transpose_bf16_kernel<<<dim3( 15, 4, 2), 256, 0, stream>>>(f3, t + 40857600, 950);
        pool_nhwc_bf16_kernel<<<dim3(nbox, 2), 256, 0, stream>>>(
            (const unsigned short*)t, boxes, bidx, out, nbox);
    } else {
        pooler_kernel<<<nbox, 256, 0, stream>>>(f0, f1, f2, f3, boxes, bidx, out, nbox);
    }
}

// Round 4
// 101.248 us; speedup vs baseline: 8.6514x; 1.0520x over previous
//
#include <hip/hip_runtime.h>
#include <hip/hip_bf16.h>

#define NOUT 7
#define NBIN 49
#define NCH 256

__device__ inline float bflo(unsigned int u) { return __uint_as_float(u << 16); }
__device__ inline float bfhi(unsigned int u) { return __uint_as_float(u & 0xffff0000u); }

// ---------- merged NCHW f32 -> NHWC bf16 transpose, all 4 levels, one launch ----------
// level block counts (nx * 4 ctiles * 2 batch): l0 7600, l1 1904, l2 480, l3 120 => 10104
__global__ __launch_bounds__(256) void transpose_all_kernel(
    const float* __restrict__ f0, const float* __restrict__ f1,
    const float* __restrict__ f2, const float* __restrict__ f3,
    unsigned short* __restrict__ ws)
{
    __shared__ float tile[64][65];

    int bid = blockIdx.x;
    const float* in;
    unsigned short* out;
    int HW;
    if (bid < 7600)      { in = f0; out = ws;            HW = 60800; }
    else if (bid < 9504) { in = f1; out = ws + 31129600; HW = 15200; bid -= 7600; }
    else if (bid < 9984) { in = f2; out = ws + 38912000; HW = 3800;  bid -= 9504; }
    else                 { in = f3; out = ws + 40857600; HW = 950;   bid -= 9984; }

    const int nx  = (HW + 63) >> 6;
    const int p0  = (bid % nx) << 6;
    const int rem = bid / nx;
    const int c0  = (rem & 3) << 6;
    const int b   = rem >> 2;

    const int tp = threadIdx.x & 63;
    const int tq = threadIdx.x >> 6;

    const size_t inb = (size_t)b * NCH * (size_t)HW;
    if (p0 + tp < HW) {
        #pragma unroll
        for (int cc = 0; cc < 64; cc += 4)
            tile[cc + tq][tp] = in[inb + (size_t)(c0 + cc + tq) * HW + (p0 + tp)];
    }
    __syncthreads();

    const size_t outb = (size_t)b * (size_t)HW * NCH;
    const int cl = (tp & 31) * 2;        // local channel pair base
    const int pr = tq * 2 + (tp >> 5);   // local p row within each group of 8
    #pragma unroll
    for (int pp = 0; pp < 64; pp += 8) {
        const int p = p0 + pp + pr;
        if (p < HW) {
            __hip_bfloat162 v;
            v.x = __float2bfloat16(tile[cl][pp + pr]);
            v.y = __float2bfloat16(tile[cl + 1][pp + pr]);
            *(__hip_bfloat162*)(out + outb + (size_t)p * NCH + (c0 + cl)) = v;
        }
    }
}

// ---------- pooling from NHWC bf16: wave-per-bin, 4 channels/lane (ushort4) ----------
__global__ __launch_bounds__(256) void pool_nhwc4_kernel(
    const unsigned short* __restrict__ ws, const float* __restrict__ boxes,
    const int* __restrict__ bidx, float* __restrict__ out, int nbox)
{
    __shared__ __align__(16) float so[NBIN * 260];   // [bin][channel], stride 260 (16B-aligned rows)

    const int n = blockIdx.x;
    if (n >= nbox) return;
    const int lane = threadIdx.x & 63;
    const int wave = threadIdx.x >> 6;

    // ---- box params (uniform) ----
    const float bx1 = boxes[4*n+0];
    const float by1 = boxes[4*n+1];
    const float bx2 = boxes[4*n+2];
    const float by2 = boxes[4*n+3];

    const float ww = bx2 - bx1 + 1.0f;
    const float hh = by2 - by1 + 1.0f;
    const float s  = sqrtf(ww * hh);
    int lvl = (int)floorf(4.0f + log2f(1e-6f + s * (1.0f / 224.0f)));
    lvl = min(max(lvl, 2), 5) - 2;

    int H, W;
    float scale;
    size_t off;
    if (lvl == 0)      { H = 200; W = 304; scale = 0.25f;    off = 0;        }
    else if (lvl == 1) { H = 100; W = 152; scale = 0.125f;   off = 31129600; }
    else if (lvl == 2) { H = 50;  W = 76;  scale = 0.0625f;  off = 38912000; }
    else               { H = 25;  W = 38;  scale = 0.03125f; off = 40857600; }

    const int b = bidx[n];
    const unsigned short* __restrict__ fb =
        ws + off + (size_t)b * (size_t)(H * W) * NCH + 4 * lane;

    const float x1 = bx1 * scale;
    const float y1 = by1 * scale;
    const float x2 = bx2 * scale;
    const float y2 = by2 * scale;
    const float roi_w = fmaxf(x2 - x1, 1.0f);
    const float roi_h = fmaxf(y2 - y1, 1.0f);
    const float bw = roi_w * (1.0f / NOUT);
    const float bh = roi_h * (1.0f / NOUT);

    const float Hf = (float)H, Wf = (float)W;

    for (int e = wave; e < NBIN; e += 4) {
        const int py = e / NOUT;
        const int px = e - py * NOUT;
        float a0 = 0.0f, a1 = 0.0f, a2 = 0.0f, a3 = 0.0f;
        #pragma unroll
        for (int iy = 0; iy < 2; ++iy) {
            #pragma unroll
            for (int ix = 0; ix < 2; ++ix) {
                float y = y1 + ((float)py + 0.25f + 0.5f * (float)iy) * bh;
                float x = x1 + ((float)px + 0.25f + 0.5f * (float)ix) * bw;
                const bool valid = (y >= -1.0f) && (y <= Hf) && (x >= -1.0f) && (x <= Wf);
                y = fminf(fmaxf(y, 0.0f), Hf - 1.0f);
                x = fminf(fmaxf(x, 0.0f), Wf - 1.0f);
                const int y0 = (int)floorf(y);
                const int x0 = (int)floorf(x);
                const int y1i = min(y0 + 1, H - 1);
                const int x1i = min(x0 + 1, W - 1);
                const float ly = y - (float)y0;
                const float lx = x - (float)x0;
                const float hy = 1.0f - ly;
                const float hx = 1.0f - lx;
                const float w00 = hy * hx, w01 = hy * lx, w10 = ly * hx, w11 = ly * lx;

                const uint2 u00 = *(const uint2*)(fb + (unsigned)(y0  * W + x0 ) * NCH);
                const uint2 u01 = *(const uint2*)(fb + (unsigned)(y0  * W + x1i) * NCH);
                const uint2 u10 = *(const uint2*)(fb + (unsigned)(y1i * W + x0 ) * NCH);
                const uint2 u11 = *(const uint2*)(fb + (unsigned)(y1i * W + x1i) * NCH);

                if (valid) {
                    a0 += w00 * bflo(u00.x) + w01 * bflo(u01.x) + w10 * bflo(u10.x) + w11 * bflo(u11.x);
                    a1 += w00 * bfhi(u00.x) + w01 * bfhi(u01.x) + w10 * bfhi(u10.x) + w11 * bfhi(u11.x);
                    a2 += w00 * bflo(u00.y) + w01 * bflo(u01.y) + w10 * bflo(u10.y) + w11 * bflo(u11.y);
                    a3 += w00 * bfhi(u00.y) + w01 * bfhi(u01.y) + w10 * bfhi(u10.y) + w11 * bfhi(u11.y);
                }
            }
        }
        float4 r;
        r.x = a0 * 0.25f; r.y = a1 * 0.25f; r.z = a2 * 0.25f; r.w = a3 * 0.25f;
        *(float4*)&so[e * 260 + 4 * lane] = r;
    }
    __syncthreads();

    // coalesced write of this box's (256,7,7) block
    float* __restrict__ outn = out + (size_t)n * (NCH * NBIN);
    for (int k = threadIdx.x; k < NCH * NBIN; k += 256) {
        const int c = k / NBIN;
        const int e = k - c * NBIN;
        outn[k] = so[e * 260 + c];
    }
}

// ---------------- fallback (round-1 kernel) if ws too small ----------------
__global__ __launch_bounds__(256) void pooler_kernel(
    const float* __restrict__ f0, const float* __restrict__ f1,
    const float* __restrict__ f2, const float* __restrict__ f3,
    const float* __restrict__ boxes, const int* __restrict__ bidx,
    float* __restrict__ out, int nbox)
{
    const int n = blockIdx.x;
    if (n >= nbox) return;
    const int c = threadIdx.x;

    const float bx1 = boxes[4*n+0];
    const float by1 = boxes[4*n+1];
    const float bx2 = boxes[4*n+2];
    const float by2 = boxes[4*n+3];

    const float ww = bx2 - bx1 + 1.0f;
    const float hh = by2 - by1 + 1.0f;
    const float s  = sqrtf(ww * hh);
    int lvl = (int)floorf(4.0f + log2f(1e-6f + s * (1.0f / 224.0f)));
    lvl = min(max(lvl, 2), 5) - 2;

    const float* f;
    int H, W;
    float scale;
    if (lvl == 0)      { f = f0; H = 200; W = 304; scale = 0.25f;    }
    else if (lvl == 1) { f = f1; H = 100; W = 152; scale = 0.125f;   }
    else if (lvl == 2) { f = f2; H = 50;  W = 76;  scale = 0.0625f;  }
    else               { f = f3; H = 25;  W = 38;  scale = 0.03125f; }

    const int b = bidx[n];
    const float* __restrict__ fb = f + ((size_t)b * NCH + c) * (size_t)(H * W);

    const float x1 = bx1 * scale;
    const float y1 = by1 * scale;
    const float x2 = bx2 * scale;
    const float y2 = by2 * scale;
    const float roi_w = fmaxf(x2 - x1, 1.0f);
    const float roi_h = fmaxf(y2 - y1, 1.0f);
    const float bw = roi_w * (1.0f / NOUT);
    const float bh = roi_h * (1.0f / NOUT);

    const float Hf = (float)H, Wf = (float)W;
    float* __restrict__ outc = out + ((size_t)n * NCH + c) * NBIN;

    for (int py = 0; py < NOUT; ++py) {
        for (int px = 0; px < NOUT; ++px) {
            float acc = 0.0f;
            #pragma unroll
            for (int iy = 0; iy < 2; ++iy) {
                #pragma unroll
                for (int ix = 0; ix < 2; ++ix) {
                    float y = y1 + ((float)py + 0.25f + 0.5f * (float)iy) * bh;
                    float x = x1 + ((float)px + 0.25f + 0.5f * (float)ix) * bw;
                    const bool valid = (y >= -1.0f) && (y <= Hf) && (x >= -1.0f) && (x <= Wf);
                    y = fminf(fmaxf(y, 0.0f), Hf - 1.0f);
                    x = fminf(fmaxf(x, 0.0f), Wf - 1.0f);
                    const int y0 = (int)floorf(y);
                    const int x0 = (int)floorf(x);
                    const int y1i = min(y0 + 1, H - 1);
                    const int x1i = min(x0 + 1, W - 1);
                    const float ly = y - (float)y0;
                    const float lx = x - (float)x0;
                    const float hy = 1.0f - ly;
                    const float hx = 1.0f - lx;
                    const float v00 = fb[y0  * W + x0 ];
                    const float v01 = fb[y0  * W + x1i];
                    const float v10 = fb[y1i * W + x0 ];
                    const float v11 = fb[y1i * W + x1i];
                    float v = hy * hx * v00 + hy * lx * v01
                            + ly * hx * v10 + ly * lx * v11;
                    acc += valid ? v : 0.0f;
                }
            }
            outc[py * NOUT + px] = acc * 0.25f;
        }
    }
}

extern "C" void kernel_launch(void* const* d_in, const int* in_sizes, int n_in,
                              void* d_out, int out_size, void* d_ws, size_t ws_size,
                              hipStream_t stream) {
    const float* f0    = (const float*)d_in[0];
    const float* f1    = (const float*)d_in[1];
    const float* f2    = (const float*)d_in[2];
    const float* f3    = (const float*)d_in[3];
    const float* boxes = (const float*)d_in[4];
    const int*   bidx  = (const int*)d_in[5];
    float*       out   = (float*)d_out;

    const int nbox = in_sizes[5];

    const size_t NEED = 41344000ull * sizeof(unsigned short);  // 82.7 MB
    if (ws_size >= NEED) {
        unsigned short* t = (unsigned short*)d_ws;
        transpose_all_kernel<<<10104, 256, 0, stream>>>(f0, f1, f2, f3, t);
        pool_nhwc4_kernel<<<nbox, 256, 0, stream>>>(t, boxes, bidx, out, nbox);
    } else {
        pooler_kernel<<<nbox, 256, 0, stream>>>(f0, f1, f2, f3, boxes, bidx, out, nbox);
    }
}